// Round 1
// 880.373 us; speedup vs baseline: 1.1429x; 1.1429x over previous
//
#include <hip/hip_runtime.h>
#include <cstdint>

// Problem constants (N=8192 nodes, K=64 neighbors incl. self, F=128 features)
#define N_NODES 8192
#define K_NB    64
#define F_DIM   128
#define SAMP_W  (2 * F_DIM + 1)          // 257 floats per sample row
#define ROWS_PER_BLK 64                  // adj row-block size
#define NBLK (N_NODES / ROWS_PER_BLK)    // 128 row blocks
#define CW   1024                        // column chunk width for phase 3
#define NCHUNK (N_NODES / CW)            // 8 chunks

// Pack (ordinal, value): u64 atomicMax compares ordinal first (high word).
// ordinal = r*K + j + 1 (0 = "unset/carry"), unique -> value bits never decide.
static __device__ __forceinline__ unsigned long long pack_uv(unsigned int ord, float v) {
    return ((unsigned long long)ord << 32) | (unsigned long long)__float_as_uint(v);
}
static __device__ __forceinline__ float unpack_v(unsigned long long p) {
    return __uint_as_float((unsigned int)(p & 0xffffffffULL));
}

// ---------------------------------------------------------------------------
// samples v2: one WG (4 waves) per node i. Wave w handles rows j = w, w+4, ...
// Row layout: [ emb[i] (128) | emb[c] (128) | sw[c] (1) ] = 1028 B.
// Lane l<32 holds node float4 in regs (loaded once, reused 16x);
// lanes 32..63 load neighbor float4 (16B-aligned, L2-resident 4MB table).
// Stores are 16B memcpy at 4B-aligned addresses (rows are 1028 B): compiler
// emits widest legal store; even the dword fallback beats v1 (4x fewer
// address calcs, scalarized idx/sw loads, no divergent branch in the loop).
// ---------------------------------------------------------------------------
__global__ __launch_bounds__(256) void samples_kernel(
    const float* __restrict__ emb, const float* __restrict__ sw,
    const int* __restrict__ idx, float* __restrict__ out)
{
    const int i = blockIdx.x;
    const int w = threadIdx.x >> 6;          // wave 0..3
    const int l = threadIdx.x & 63;          // lane
    float4 nd4 = make_float4(0.f, 0.f, 0.f, 0.f);
    if (l < 32) nd4 = *reinterpret_cast<const float4*>(&emb[i * F_DIM + 4 * l]);
    #pragma unroll 4
    for (int j = w; j < K_NB; j += 4) {
        const int c = (j < K_NB - 1) ? idx[i * (K_NB - 1) + j] : i;  // wave-uniform
        const float swc = sw[c];
        float4 v;
        if (l < 32) v = nd4;                                          // node half
        else        v = *reinterpret_cast<const float4*>(&emb[c * F_DIM + 4 * (l - 32)]);
        const size_t base = (size_t)(i * K_NB + j) * SAMP_W;
        __builtin_memcpy(out + base + 4 * l, &v, sizeof(float4));     // 16B, 4B-aligned
        if (l == 0) out[base + 2 * F_DIM] = swc;                      // col 256
    }
}

// ---------------------------------------------------------------------------
// P1: per row-block b, per column c: packed max-ordinal update (0 if none).
// LDS line of 8192 u64 (64 KB). 4096 updates per block via atomicMax.
// ---------------------------------------------------------------------------
__global__ __launch_bounds__(256) void p1_kernel(
    const int* __restrict__ idx, const float* __restrict__ edge,
    unsigned long long* __restrict__ S)
{
    __shared__ unsigned long long line[N_NODES];      // 64 KB
    const int b = blockIdx.x;
    const int t = threadIdx.x;
    for (int k = t; k < N_NODES; k += 256) line[k] = 0ULL;
    __syncthreads();
    for (int u = t; u < ROWS_PER_BLK * K_NB; u += 256) {
        const int r = b * ROWS_PER_BLK + (u >> 6);
        const int j = u & 63;
        const int c = (j < K_NB - 1) ? idx[r * (K_NB - 1) + j] : r;
        const float v = edge[r * K_NB + j];
        atomicMax(&line[c], pack_uv((unsigned)(r * K_NB + j + 1), v));
    }
    __syncthreads();
    for (int k = t; k < N_NODES; k += 256) S[b * N_NODES + k] = line[k];
}

// ---------------------------------------------------------------------------
// P2: per column, forward scan over block summaries -> carry-in value per
// (block, column). 128 blocks x 64 threads: spread the latency-bound scan
// over 128 CUs instead of 32 (v1 used 32x256 -> 224 CUs idle).
// ---------------------------------------------------------------------------
__global__ __launch_bounds__(64) void p2_kernel(
    const unsigned long long* __restrict__ S, float* __restrict__ carry)
{
    const int c = blockIdx.x * 64 + threadIdx.x;      // 8192 threads
    unsigned long long run = 0ULL;                    // value 0.0f initially
    #pragma unroll 8
    for (int b = 0; b < NBLK; ++b) {
        carry[b * N_NODES + c] = unpack_v(run);       // carry = state BEFORE block b
        const unsigned long long s = S[b * N_NODES + c];
        if (s != 0ULL) run = s;
    }
}

// ---------------------------------------------------------------------------
// P3 v2: one WG per (row-block, column-chunk), CW=1024 (8 KB LDS, 1024 blocks
// = 4/CU). Replay the 64 rows in order. KEY CHANGE vs v1: raw s_barrier with
// lgkmcnt(0)-only waits -- __syncthreads() emitted s_waitcnt vmcnt(0) which
// forced every row's adj stores to drain to HBM before the next row's LDS
// atomics. Barriers here order LDS only; adj float4 stores stay in flight
// across rows (fire-and-forget, drained at kernel end).
// ---------------------------------------------------------------------------
__global__ __launch_bounds__(256) void p3_kernel(
    const int* __restrict__ idx, const float* __restrict__ edge,
    const float* __restrict__ carry, float* __restrict__ adj)
{
    __shared__ alignas(16) unsigned long long line[CW];   // 8 KB
    const int b  = blockIdx.x;                            // row block
    const int c0 = blockIdx.y * CW;                       // chunk base column
    const int t  = threadIdx.x;
    const int k4 = t * 4;                                 // 4 columns per thread

    {   // init line from carry (vectorized read, 4 packed LDS writes)
        const float4 cv = *reinterpret_cast<const float4*>(&carry[(size_t)b * N_NODES + c0 + k4]);
        line[k4 + 0] = pack_uv(0u, cv.x);
        line[k4 + 1] = pack_uv(0u, cv.y);
        line[k4 + 2] = pack_uv(0u, cv.z);
        line[k4 + 3] = pack_uv(0u, cv.w);
    }
    asm volatile("s_waitcnt lgkmcnt(0)" ::: "memory");
    __builtin_amdgcn_s_barrier();

    for (int rr = 0; rr < ROWS_PER_BLK; ++rr) {
        const int r = b * ROWS_PER_BLK + rr;
        // apply row r's updates (<=64, packed atomicMax handles dup columns)
        if (t < K_NB) {
            const int c = (t < K_NB - 1) ? idx[r * (K_NB - 1) + t] : r;
            const unsigned cc = (unsigned)(c - c0);
            if (cc < (unsigned)CW) {
                atomicMax(&line[cc], pack_uv((unsigned)(r * K_NB + t + 1), edge[r * K_NB + t]));
            }
        }
        asm volatile("s_waitcnt lgkmcnt(0)" ::: "memory");   // LDS atomics visible
        __builtin_amdgcn_s_barrier();

        // stream line -> adj[r][chunk]: 2x ds_read_b128 + 1 float4 store/thread
        const ulonglong2 p0 = *reinterpret_cast<const ulonglong2*>(&line[k4]);
        const ulonglong2 p1 = *reinterpret_cast<const ulonglong2*>(&line[k4 + 2]);
        float4 v;
        v.x = unpack_v(p0.x); v.y = unpack_v(p0.y);
        v.z = unpack_v(p1.x); v.w = unpack_v(p1.y);
        *reinterpret_cast<float4*>(&adj[(size_t)r * N_NODES + c0 + k4]) = v;

        asm volatile("s_waitcnt lgkmcnt(0)" ::: "memory");   // reads done before next atomics
        __builtin_amdgcn_s_barrier();
    }
}

// ---------------------------------------------------------------------------
// Launch. d_out = [samples (134,742,016 f32) | adj (67,108,864 f32)].
// Scratch (S: 8 MB, carry: 4 MB) lives at the FRONT of the samples region;
// samples_kernel runs LAST and overwrites it (stream-ordered, graph-safe) so
// we never depend on ws_size.
// ---------------------------------------------------------------------------
extern "C" void kernel_launch(void* const* d_in, const int* in_sizes, int n_in,
                              void* d_out, int out_size, void* d_ws, size_t ws_size,
                              hipStream_t stream)
{
    const float* emb  = (const float*)d_in[0];
    const float* sw   = (const float*)d_in[1];
    const int*   idx  = (const int*)d_in[2];
    const float* edge = (const float*)d_in[3];

    float* out      = (float*)d_out;
    float* samples  = out;
    float* adj      = out + (size_t)N_NODES * K_NB * SAMP_W;

    unsigned long long* S = (unsigned long long*)d_out;                  // 8 MB
    float* carry = (float*)((char*)d_out + (size_t)NBLK * N_NODES * 8);  // 4 MB

    p1_kernel<<<NBLK, 256, 0, stream>>>(idx, edge, S);
    p2_kernel<<<N_NODES / 64, 64, 0, stream>>>(S, carry);
    p3_kernel<<<dim3(NBLK, NCHUNK), 256, 0, stream>>>(idx, edge, carry, adj);
    samples_kernel<<<N_NODES, 256, 0, stream>>>(emb, sw, idx, samples);
}